// Round 4
// baseline (473.805 us; speedup 1.0000x reference)
//
#include <hip/hip_runtime.h>
#include <stdint.h>

#define DIM   1024
#define HEADS 16
#define DH    64
#define B_    4
#define N_    1024
#define P_    1024
#define J_    2048
#define SCALE_ 8.0f
#define WIND  16

typedef __attribute__((ext_vector_type(8))) short bf16x8;
typedef __attribute__((ext_vector_type(4))) float f32x4;

typedef __attribute__((address_space(1))) void* as1_t;
typedef __attribute__((address_space(3))) void* as3_t;

static __device__ __forceinline__ unsigned short f2bf(float f) {
    union { float f; unsigned u; } v; v.f = f;
    unsigned r = v.u + 0x7fffu + ((v.u >> 16) & 1u);
    return (unsigned short)(r >> 16);
}
static __device__ __forceinline__ bf16x8 ld_bf16x8(const void* p) {
    int4 v = *reinterpret_cast<const int4*>(p);
    return __builtin_bit_cast(bf16x8, v);
}
static __device__ __forceinline__ bf16x8 packbf8(const float* f) {
    bf16x8 r;
    #pragma unroll
    for (int j = 0; j < 8; ++j) r[j] = (short)f2bf(f[j]);
    return r;
}
static __device__ __forceinline__ void gl_lds16(const void* g, void* l) {
    __builtin_amdgcn_global_load_lds((as1_t)(size_t)g, (as3_t)l, 16, 0, 0);
}

// ---------------- f32 -> bf16 convert: all three weight matrices in one launch ----------------
__global__ __launch_bounds__(256) void k_cvt3(
    const float* __restrict__ wq, const float* __restrict__ wkv, const float* __restrict__ wo,
    unsigned short* __restrict__ dq, unsigned short* __restrict__ dkv, unsigned short* __restrict__ dwo)
{
    int i = blockIdx.x * 256 + threadIdx.x;
    const float* s; unsigned short* d; int off;
    if (i < 262144)      { s = wq;  d = dq;  off = i; }
    else if (i < 294912) { s = wkv; d = dkv; off = i - 262144; }
    else                 { s = wo;  d = dwo; off = i - 294912; }
    float4 v = reinterpret_cast<const float4*>(s)[off];
    uint2 o;
    o.x = (unsigned)f2bf(v.x) | ((unsigned)f2bf(v.y) << 16);
    o.y = (unsigned)f2bf(v.z) | ((unsigned)f2bf(v.w) << 16);
    reinterpret_cast<uint2*>(d)[off] = o;
}

// ---------------- LayerNorm(x) -> xn bf16 ; raw x,prefix -> kvin bf16 ----------------
__global__ __launch_bounds__(256) void k_ln_cvt(
    const float* __restrict__ x, const float* __restrict__ prefix,
    const float* __restrict__ gamma,
    unsigned short* __restrict__ xn, unsigned short* __restrict__ kvin)
{
    __shared__ float red[8];
    const int bid = blockIdx.x;
    const int t = threadIdx.x;
    const int w = t >> 6, lane = t & 63;
    if (bid < B_ * N_) {
        const int b = bid >> 10, n = bid & 1023;
        float4 v = reinterpret_cast<const float4*>(x + (size_t)bid * DIM)[t];
        uint2 raw;
        raw.x = (unsigned)f2bf(v.x) | ((unsigned)f2bf(v.y) << 16);
        raw.y = (unsigned)f2bf(v.z) | ((unsigned)f2bf(v.w) << 16);
        reinterpret_cast<uint2*>(kvin + ((size_t)b * J_ + P_ + n) * DIM)[t] = raw;
        float s = v.x + v.y + v.z + v.w;
        float ss = v.x*v.x + v.y*v.y + v.z*v.z + v.w*v.w;
        #pragma unroll
        for (int off = 32; off > 0; off >>= 1) {
            s  += __shfl_xor(s, off, 64);
            ss += __shfl_xor(ss, off, 64);
        }
        if (lane == 0) { red[w*2] = s; red[w*2+1] = ss; }
        __syncthreads();
        s  = red[0] + red[2] + red[4] + red[6];
        ss = red[1] + red[3] + red[5] + red[7];
        float mu = s * (1.0f / DIM);
        float var = ss * (1.0f / DIM) - mu * mu;
        float rs = rsqrtf(var + 1e-5f);
        float4 g = reinterpret_cast<const float4*>(gamma)[t];
        float o0 = (v.x - mu) * rs * g.x;
        float o1 = (v.y - mu) * rs * g.y;
        float o2 = (v.z - mu) * rs * g.z;
        float o3 = (v.w - mu) * rs * g.w;
        uint2 on;
        on.x = (unsigned)f2bf(o0) | ((unsigned)f2bf(o1) << 16);
        on.y = (unsigned)f2bf(o2) | ((unsigned)f2bf(o3) << 16);
        reinterpret_cast<uint2*>(xn + (size_t)bid * DIM)[t] = on;
    } else {
        const int r = bid - B_ * N_;
        float4 v = reinterpret_cast<const float4*>(prefix + (size_t)r * DIM)[t];
        const int b = r >> 10, jr = r & 1023;
        uint2 raw;
        raw.x = (unsigned)f2bf(v.x) | ((unsigned)f2bf(v.y) << 16);
        raw.y = (unsigned)f2bf(v.z) | ((unsigned)f2bf(v.w) << 16);
        reinterpret_cast<uint2*>(kvin + ((size_t)b * J_ + jr) * DIM)[t] = raw;
    }
}

// ---------------- GEMM: C[M,N] f32 = A[M,K]bf16 * B[N,K]bf16^T ----------------
// tile 128(M)x64(N), BK=64, 4 waves in 2x2, each wave 64x32 (4x2 frags).
// 512 blocks for the 4096x1024 GEMMs -> 2 blocks/CU, 8 waves/CU of overlap.
__global__ __launch_bounds__(256) void k_gemm_bt(
    const unsigned short* __restrict__ A, const unsigned short* __restrict__ Bm,
    float* __restrict__ C, int K, int ldc)
{
    __shared__ __align__(16) unsigned short As[128 * 64];
    __shared__ __align__(16) unsigned short Bs[64 * 64];
    const int tid = threadIdx.x;
    const int w = tid >> 6, lane = tid & 63;
    const int lg = lane >> 4, ll = lane & 15;
    const int m0 = blockIdx.y * 128, n0 = blockIdx.x * 64;
    const int wm = w >> 1, wn = w & 1;
    f32x4 acc[4][2];
    #pragma unroll
    for (int i = 0; i < 4; ++i)
        #pragma unroll
        for (int j = 0; j < 2; ++j)
            acc[i][j] = f32x4{0.f, 0.f, 0.f, 0.f};

    for (int k0 = 0; k0 < K; k0 += 64) {
        const unsigned short* Ab = A + (size_t)m0 * K + k0;
        const unsigned short* Bb = Bm + (size_t)n0 * K + k0;
        #pragma unroll
        for (int s = 0; s < 4; ++s) {
            int chunk = s * 256 + w * 64 + lane;
            int row = chunk >> 3, c = chunk & 7;
            int sc = (c ^ (row & 7)) * 8;
            gl_lds16(Ab + (size_t)row * K + sc, &As[chunk * 8]);
        }
        #pragma unroll
        for (int s = 0; s < 2; ++s) {
            int chunk = s * 256 + w * 64 + lane;
            int row = chunk >> 3, c = chunk & 7;
            int sc = (c ^ (row & 7)) * 8;
            gl_lds16(Bb + (size_t)row * K + sc, &Bs[chunk * 8]);
        }
        __syncthreads();
        bf16x8 af[4][2], bfr[2][2];
        #pragma unroll
        for (int ms = 0; ms < 4; ++ms) {
            #pragma unroll
            for (int ks = 0; ks < 2; ++ks) {
                int r = wm * 64 + ms * 16 + ll;
                int gc = ks * 4 + lg;
                af[ms][ks] = ld_bf16x8((const char*)As + r * 128 + ((gc ^ (r & 7)) << 4));
            }
        }
        #pragma unroll
        for (int ns = 0; ns < 2; ++ns) {
            #pragma unroll
            for (int ks = 0; ks < 2; ++ks) {
                int r = wn * 32 + ns * 16 + ll;
                int gc = ks * 4 + lg;
                bfr[ns][ks] = ld_bf16x8((const char*)Bs + r * 128 + ((gc ^ (r & 7)) << 4));
            }
        }
        #pragma unroll
        for (int ks = 0; ks < 2; ++ks)
            #pragma unroll
            for (int ms = 0; ms < 4; ++ms)
                #pragma unroll
                for (int ns = 0; ns < 2; ++ns)
                    acc[ms][ns] = __builtin_amdgcn_mfma_f32_16x16x32_bf16(
                        af[ms][ks], bfr[ns][ks], acc[ms][ns], 0, 0, 0);
        __syncthreads();
    }
    #pragma unroll
    for (int ms = 0; ms < 4; ++ms) {
        #pragma unroll
        for (int ns = 0; ns < 2; ++ns) {
            int col = n0 + wn * 32 + ns * 16 + ll;
            int rbase = m0 + wm * 64 + ms * 16 + lg * 4;
            #pragma unroll
            for (int rr = 0; rr < 4; ++rr)
                C[(size_t)(rbase + rr) * ldc + col] = acc[ms][ns][rr];
        }
    }
}

// ---------------- KV epilogue: K l2norm -> bf16 [B,J,DH]; V -> Vt bf16 [B,DH,J] ----------------
__global__ __launch_bounds__(256) void k_kv_epi(const float* __restrict__ KVg,
    const float* __restrict__ k_scale, unsigned short* __restrict__ Kb,
    unsigned short* __restrict__ Vt)
{
    __shared__ __align__(16) unsigned short Vs[64 * 64];
    const int blk = blockIdx.x;
    const int t = threadIdx.x;
    const int w = t >> 6, lane = t & 63;
    const int rowbase = blk * 64;
    const int b = rowbase >> 11;
    const int jloc = rowbase & 2047;
    float kscale = k_scale[lane];
    #pragma unroll
    for (int it = 0; it < 16; ++it) {
        int row = rowbase + w * 16 + it;
        float v = KVg[(size_t)row * 128 + lane];
        float ss = v * v;
        #pragma unroll
        for (int off = 32; off > 0; off >>= 1) ss += __shfl_xor(ss, off, 64);
        float inv = 1.0f / fmaxf(sqrtf(ss), 1e-12f);
        Kb[(size_t)row * DH + lane] = f2bf(v * inv * kscale);
    }
    const int r = t >> 2;
    const int cb = (t & 3) * 16;
    #pragma unroll
    for (int c4 = 0; c4 < 4; ++c4) {
        float4 v = *reinterpret_cast<const float4*>(&KVg[(size_t)(rowbase + r) * 128 + 64 + cb + c4 * 4]);
        Vs[(cb + c4 * 4 + 0) * 64 + r] = f2bf(v.x);
        Vs[(cb + c4 * 4 + 1) * 64 + r] = f2bf(v.y);
        Vs[(cb + c4 * 4 + 2) * 64 + r] = f2bf(v.z);
        Vs[(cb + c4 * 4 + 3) * 64 + r] = f2bf(v.w);
    }
    __syncthreads();
    const int d = t >> 2;
    const int jl = (t & 3) * 16;
    const int4* vsp = reinterpret_cast<const int4*>(&Vs[d * 64 + jl]);
    int4* dst = reinterpret_cast<int4*>(&Vt[((size_t)(b * 64 + d)) * J_ + jloc + jl]);
    dst[0] = vsp[0];
    dst[1] = vsp[1];
}

// ---------------- fused masked attention, flash-style, software-pipelined ----------------
// Per-tile chain was latency-bound (R1: MfmaUtil 2%, VALU 12%, nothing busy).
// Pipeline: bias(t+1) prefetched into regs a full tile ahead (HBM ~900cy covered);
// V issued at top of tile (QK+softmax covers it); K first so QK's vmcnt leaves
// V/bias outstanding. 2-deep manual unroll, named buffers (no dyn indexing).
__global__ __launch_bounds__(256, 3) void k_attn(
    const float* __restrict__ Qg, const float* __restrict__ q_scale,
    const unsigned short* __restrict__ Kb, const unsigned short* __restrict__ Vt,
    const float* __restrict__ bias, unsigned short* __restrict__ AO)
{
    __shared__ __align__(16) unsigned short Ps[4][16 * 64];
    const int t = threadIdx.x, w = t >> 6, lane = t & 63;
    const int lg = lane >> 4, ll = lane & 15;
    const int qt = 15 - (blockIdx.x & 15);
    const int h = (blockIdx.x >> 4) & 15;
    const int b = blockIdx.x >> 8;
    const int qbase = qt * 64;
    const float NEG_INF = -__builtin_inff();

    bf16x8 qf[2];
    {
        const float* qrow = Qg + (size_t)(b * N_ + qbase + w * 16 + ll) * DIM + h * DH;
        float qv[16];
        #pragma unroll
        for (int ks = 0; ks < 2; ++ks) {
            float4 a = *reinterpret_cast<const float4*>(qrow + ks * 32 + lg * 8);
            float4 c = *reinterpret_cast<const float4*>(qrow + ks * 32 + lg * 8 + 4);
            qv[ks*8+0]=a.x; qv[ks*8+1]=a.y; qv[ks*8+2]=a.z; qv[ks*8+3]=a.w;
            qv[ks*8+4]=c.x; qv[ks*8+5]=c.y; qv[ks*8+6]=c.z; qv[ks*8+7]=c.w;
        }
        float ss = 0.f;
        #pragma unroll
        for (int j2 = 0; j2 < 16; ++j2) ss += qv[j2] * qv[j2];
        ss += __shfl_xor(ss, 16, 64);
        ss += __shfl_xor(ss, 32, 64);
        float inv = 1.0f / fmaxf(sqrtf(ss), 1e-12f);
        #pragma unroll
        for (int ks = 0; ks < 2; ++ks) {
            float4 s1 = *reinterpret_cast<const float4*>(q_scale + ks * 32 + lg * 8);
            float4 s2 = *reinterpret_cast<const float4*>(q_scale + ks * 32 + lg * 8 + 4);
            qv[ks*8+0] *= inv * s1.x; qv[ks*8+1] *= inv * s1.y;
            qv[ks*8+2] *= inv * s1.z; qv[ks*8+3] *= inv * s1.w;
            qv[ks*8+4] *= inv * s2.x; qv[ks*8+5] *= inv * s2.y;
            qv[ks*8+6] *= inv * s2.z; qv[ks*8+7] *= inv * s2.w;
        }
        qf[0] = packbf8(&qv[0]);
        qf[1] = packbf8(&qv[8]);
    }

    float mrow[4], lrow[4];
    f32x4 o[4];
    #pragma unroll
    for (int rr = 0; rr < 4; ++rr) { mrow[rr] = -1e30f; lrow[rr] = 0.f; }
    #pragma unroll
    for (int ds = 0; ds < 4; ++ds) o[ds] = f32x4{0.f, 0.f, 0.f, 0.f};

    const unsigned short* Kbb = Kb + (size_t)b * J_ * DH;
    const unsigned short* Vbb = Vt + (size_t)b * 64 * J_;
    char* pbase = (char*)&Ps[w][0];

    const int npre = (qt > 0) ? 2 : 1;
    const int nt = npre + qt + 1;
    // bias row base for this thread (i = qbase + w*16 + lg*4 + rr)
    const float* bias_tb = bias + ((size_t)h * N_ + qbase + w * 16 + lg * 4) * N_ + ll;

    float bbA[16], bbB[16];

#define LOAD_BIAS(IDX, BB)                                                     \
    do {                                                                       \
        int _i = (IDX);                                                        \
        if (_i < nt && _i >= npre) {                                           \
            const float* _bp = bias_tb + (size_t)(_i - npre) * 64;             \
            _Pragma("unroll")                                                  \
            for (int _ns = 0; _ns < 4; ++_ns)                                  \
                _Pragma("unroll")                                              \
                for (int _rr = 0; _rr < 4; ++_rr)                              \
                    BB[_ns * 4 + _rr] = _bp[(size_t)_rr * N_ + _ns * 16];      \
        }                                                                      \
    } while (0)

#define STEP(IDX, BBCUR, BBNXT)                                                \
    do {                                                                       \
        const int _idx = (IDX);                                                \
        const bool is_pre = _idx < npre;                                       \
        const int tpre = (qt > 0) ? (qt - 1 + _idx) : 0;                       \
        const int kt = _idx - npre;                                            \
        const int kvrow = is_pre ? tpre * 64 : P_ + kt * 64;                   \
        const unsigned short* Kp = Kbb + (size_t)kvrow * DH;                   \
        const unsigned short* Vp = Vbb + kvrow;                                \
        bf16x8 kf[4][2];                                                       \
        _Pragma("unroll")                                                      \
        for (int ns = 0; ns < 4; ++ns)                                         \
            _Pragma("unroll")                                                  \
            for (int ks = 0; ks < 2; ++ks)                                     \
                kf[ns][ks] = ld_bf16x8(Kp + (size_t)(ns * 16 + ll) * DH + ks * 32 + lg * 8); \
        bf16x8 vf[4][2];                                                       \
        _Pragma("unroll")                                                      \
        for (int ds = 0; ds < 4; ++ds)                                         \
            _Pragma("unroll")                                                  \
            for (int ks = 0; ks < 2; ++ks)                                     \
                vf[ds][ks] = ld_bf16x8(Vp + (size_t)(ds * 16 + ll) * J_ + ks * 32 + lg * 8); \
        LOAD_BIAS(_idx + 1, BBNXT);                                            \
        f32x4 sv[4];                                                           \
        _Pragma("unroll")                                                      \
        for (int ns = 0; ns < 4; ++ns) {                                       \
            f32x4 s = f32x4{0.f, 0.f, 0.f, 0.f};                               \
            _Pragma("unroll")                                                  \
            for (int ks = 0; ks < 2; ++ks)                                     \
                s = __builtin_amdgcn_mfma_f32_16x16x32_bf16(qf[ks], kf[ns][ks], s, 0, 0, 0); \
            sv[ns] = s;                                                        \
        }                                                                      \
        _Pragma("unroll")                                                      \
        for (int ns = 0; ns < 4; ++ns) {                                       \
            _Pragma("unroll")                                                  \
            for (int rr = 0; rr < 4; ++rr) {                                   \
                int i = qbase + w * 16 + lg * 4 + rr;                          \
                int key = ns * 16 + ll;                                        \
                float val = sv[ns][rr] * SCALE_;                               \
                if (is_pre) {                                                  \
                    int cc = kvrow + key;                                      \
                    bool ok = (i >= cc) && (i - cc < WIND);                    \
                    val = ok ? val : NEG_INF;                                  \
                } else {                                                       \
                    int j2 = kt * 64 + key;                                    \
                    val += BBCUR[ns * 4 + rr];                                 \
                    if (j2 > i) val = NEG_INF;                                 \
                }                                                              \
                sv[ns][rr] = val;                                              \
            }                                                                  \
        }                                                                      \
        float al[4];                                                           \
        _Pragma("unroll")                                                      \
        for (int rr = 0; rr < 4; ++rr) {                                       \
            float mx = fmaxf(fmaxf(sv[0][rr], sv[1][rr]), fmaxf(sv[2][rr], sv[3][rr])); \
            _Pragma("unroll")                                                  \
            for (int off = 1; off < 16; off <<= 1) mx = fmaxf(mx, __shfl_xor(mx, off, 64)); \
            float mn = fmaxf(mrow[rr], mx);                                    \
            al[rr] = __expf(mrow[rr] - mn);                                    \
            mrow[rr] = mn;                                                     \
        }                                                                      \
        float rsum[4];                                                         \
        _Pragma("unroll")                                                      \
        for (int rr = 0; rr < 4; ++rr) rsum[rr] = 0.f;                         \
        _Pragma("unroll")                                                      \
        for (int ns = 0; ns < 4; ++ns) {                                       \
            _Pragma("unroll")                                                  \
            for (int rr = 0; rr < 4; ++rr) {                                   \
                float p = __expf(sv[ns][rr] - mrow[rr]);                       \
                sv[ns][rr] = p;                                                \
                rsum[rr] += p;                                                 \
            }                                                                  \
        }                                                                      \
        _Pragma("unroll")                                                      \
        for (int rr = 0; rr < 4; ++rr) {                                       \
            float rsv = rsum[rr];                                              \
            _Pragma("unroll")                                                  \
            for (int off = 1; off < 16; off <<= 1) rsv += __shfl_xor(rsv, off, 64); \
            lrow[rr] = lrow[rr] * al[rr] + rsv;                                \
        }                                                                      \
        _Pragma("unroll")                                                      \
        for (int ds = 0; ds < 4; ++ds)                                         \
            _Pragma("unroll")                                                  \
            for (int rr = 0; rr < 4; ++rr)                                     \
                o[ds][rr] *= al[rr];                                           \
        _Pragma("unroll")                                                      \
        for (int ns = 0; ns < 4; ++ns) {                                       \
            _Pragma("unroll")                                                  \
            for (int rr = 0; rr < 4; ++rr) {                                   \
                int ql = lg * 4 + rr;                                          \
                int jc = ns * 16 + ll;                                         \
                int byteoff = ql * 128 + (((jc >> 3) ^ (ql & 7)) << 4) + (jc & 7) * 2; \
                *reinterpret_cast<unsigned short*>(pbase + byteoff) = f2bf(sv[ns][rr]); \
            }                                                                  \
        }                                                                      \
        bf16x8 pa[2];                                                          \
        _Pragma("unroll")                                                      \
        for (int ks = 0; ks < 2; ++ks) {                                       \
            int gc = ks * 4 + lg;                                              \
            pa[ks] = ld_bf16x8(pbase + ll * 128 + ((gc ^ (ll & 7)) << 4));     \
        }                                                                      \
        _Pragma("unroll")                                                      \
        for (int ds = 0; ds < 4; ++ds)                                         \
            _Pragma("unroll")                                                  \
            for (int ks = 0; ks < 2; ++ks)                                     \
                o[ds] = __builtin_amdgcn_mfma_f32_16x16x32_bf16(pa[ks], vf[ds][ks], o[ds], 0, 0, 0); \
    } while (0)

    LOAD_BIAS(0, bbA);
    int tc = 0;
    while (tc < nt) {
        STEP(tc, bbA, bbB);
        ++tc;
        if (tc >= nt) break;
        STEP(tc, bbB, bbA);
        ++tc;
    }
#undef STEP
#undef LOAD_BIAS

    #pragma unroll
    for (int rr = 0; rr < 4; ++rr) {
        float inv = 1.0f / lrow[rr];
        int i = qbase + w * 16 + lg * 4 + rr;
        unsigned short* orow = AO + ((size_t)b * N_ + i) * DIM + h * DH;
        #pragma unroll
        for (int ds = 0; ds < 4; ++ds)
            orow[ds * 16 + ll] = f2bf(o[ds][rr] * inv);
    }
}

extern "C" void kernel_launch(void* const* d_in, const int* in_sizes, int n_in,
                              void* d_out, int out_size, void* d_ws, size_t ws_size,
                              hipStream_t stream)
{
    const float* x       = (const float*)d_in[0];
    const float* prefix  = (const float*)d_in[1];
    const float* bias    = (const float*)d_in[2];
    const float* gamma   = (const float*)d_in[3];
    const float* Wq      = (const float*)d_in[4];
    const float* Wkv     = (const float*)d_in[5];
    const float* q_scale = (const float*)d_in[6];
    const float* k_scale = (const float*)d_in[7];
    const float* Wo      = (const float*)d_in[8];
    float* out = (float*)d_out;

    char* ws = (char*)d_ws;
    unsigned short* xn   = (unsigned short*)(ws);              // 8 MB  [4096,1024] bf16
    unsigned short* kvin = (unsigned short*)(ws + 8388608);    // 16 MB [4,2048,1024] bf16
    unsigned short* wqb  = (unsigned short*)(ws + 25165824);   // 2 MB
    unsigned short* wkvb = (unsigned short*)(ws + 27262976);   // 256 KB
    unsigned short* wob  = (unsigned short*)(ws + 27525120);   // 2 MB
    float* qg            = (float*)(ws + 29622272);            // 16 MB [4096,1024] f32
    float* kvg           = (float*)(ws + 46399488);            // 4 MB  [8192,128] f32
    unsigned short* kb   = (unsigned short*)(ws + 58982400);   // 1 MB  [B,J,DH] bf16
    unsigned short* vt   = (unsigned short*)(ws + 60030976);   // 1 MB  [B,DH,J] bf16
    unsigned short* ao   = (unsigned short*)(ws + 61079552);   // 8 MB  [4096,1024] bf16

    k_cvt3<<<2176, 256, 0, stream>>>(Wq, Wkv, Wo, wqb, wkvb, wob);
    k_ln_cvt<<<8192, 256, 0, stream>>>(x, prefix, gamma, xn, kvin);
    k_gemm_bt<<<dim3(16, 32), 256, 0, stream>>>(xn, wqb, qg, 1024, 1024);
    k_gemm_bt<<<dim3(2, 64), 256, 0, stream>>>(kvin, wkvb, kvg, 1024, 128);
    k_kv_epi<<<128, 256, 0, stream>>>(kvg, k_scale, kb, vt);
    k_attn<<<1024, 256, 0, stream>>>(qg, q_scale, kb, vt, bias, ao);
    k_gemm_bt<<<dim3(16, 32), 256, 0, stream>>>(ao, wob, out, 1024, 1024);
}

// Round 5
// 353.409 us; speedup vs baseline: 1.3407x; 1.3407x over previous
//
#include <hip/hip_runtime.h>
#include <stdint.h>

#define DIM   1024
#define HEADS 16
#define DH    64
#define B_    4
#define N_    1024
#define P_    1024
#define J_    2048
#define SCALE_ 8.0f
#define WIND  16

typedef __attribute__((ext_vector_type(8))) short bf16x8;
typedef __attribute__((ext_vector_type(4))) float f32x4;

typedef __attribute__((address_space(1))) void* as1_t;
typedef __attribute__((address_space(3))) void* as3_t;

static __device__ __forceinline__ unsigned short f2bf(float f) {
    union { float f; unsigned u; } v; v.f = f;
    unsigned r = v.u + 0x7fffu + ((v.u >> 16) & 1u);
    return (unsigned short)(r >> 16);
}
static __device__ __forceinline__ bf16x8 ld_bf16x8(const void* p) {
    int4 v = *reinterpret_cast<const int4*>(p);
    return __builtin_bit_cast(bf16x8, v);
}
static __device__ __forceinline__ bf16x8 packbf8(const float* f) {
    bf16x8 r;
    #pragma unroll
    for (int j = 0; j < 8; ++j) r[j] = (short)f2bf(f[j]);
    return r;
}
static __device__ __forceinline__ void gl_lds16(const void* g, void* l) {
    __builtin_amdgcn_global_load_lds((as1_t)(size_t)g, (as3_t)l, 16, 0, 0);
}

// ---------------- f32 -> bf16 convert: all three weight matrices in one launch ----------------
__global__ __launch_bounds__(256) void k_cvt3(
    const float* __restrict__ wq, const float* __restrict__ wkv, const float* __restrict__ wo,
    unsigned short* __restrict__ dq, unsigned short* __restrict__ dkv, unsigned short* __restrict__ dwo)
{
    int i = blockIdx.x * 256 + threadIdx.x;
    const float* s; unsigned short* d; int off;
    if (i < 262144)      { s = wq;  d = dq;  off = i; }
    else if (i < 294912) { s = wkv; d = dkv; off = i - 262144; }
    else                 { s = wo;  d = dwo; off = i - 294912; }
    float4 v = reinterpret_cast<const float4*>(s)[off];
    uint2 o;
    o.x = (unsigned)f2bf(v.x) | ((unsigned)f2bf(v.y) << 16);
    o.y = (unsigned)f2bf(v.z) | ((unsigned)f2bf(v.w) << 16);
    reinterpret_cast<uint2*>(d)[off] = o;
}

// ---------------- LayerNorm(x) -> xn bf16 ; raw x,prefix -> kvin bf16 ----------------
__global__ __launch_bounds__(256) void k_ln_cvt(
    const float* __restrict__ x, const float* __restrict__ prefix,
    const float* __restrict__ gamma,
    unsigned short* __restrict__ xn, unsigned short* __restrict__ kvin)
{
    __shared__ float red[8];
    const int bid = blockIdx.x;
    const int t = threadIdx.x;
    const int w = t >> 6, lane = t & 63;
    if (bid < B_ * N_) {
        const int b = bid >> 10, n = bid & 1023;
        float4 v = reinterpret_cast<const float4*>(x + (size_t)bid * DIM)[t];
        uint2 raw;
        raw.x = (unsigned)f2bf(v.x) | ((unsigned)f2bf(v.y) << 16);
        raw.y = (unsigned)f2bf(v.z) | ((unsigned)f2bf(v.w) << 16);
        reinterpret_cast<uint2*>(kvin + ((size_t)b * J_ + P_ + n) * DIM)[t] = raw;
        float s = v.x + v.y + v.z + v.w;
        float ss = v.x*v.x + v.y*v.y + v.z*v.z + v.w*v.w;
        #pragma unroll
        for (int off = 32; off > 0; off >>= 1) {
            s  += __shfl_xor(s, off, 64);
            ss += __shfl_xor(ss, off, 64);
        }
        if (lane == 0) { red[w*2] = s; red[w*2+1] = ss; }
        __syncthreads();
        s  = red[0] + red[2] + red[4] + red[6];
        ss = red[1] + red[3] + red[5] + red[7];
        float mu = s * (1.0f / DIM);
        float var = ss * (1.0f / DIM) - mu * mu;
        float rs = rsqrtf(var + 1e-5f);
        float4 g = reinterpret_cast<const float4*>(gamma)[t];
        float o0 = (v.x - mu) * rs * g.x;
        float o1 = (v.y - mu) * rs * g.y;
        float o2 = (v.z - mu) * rs * g.z;
        float o3 = (v.w - mu) * rs * g.w;
        uint2 on;
        on.x = (unsigned)f2bf(o0) | ((unsigned)f2bf(o1) << 16);
        on.y = (unsigned)f2bf(o2) | ((unsigned)f2bf(o3) << 16);
        reinterpret_cast<uint2*>(xn + (size_t)bid * DIM)[t] = on;
    } else {
        const int r = bid - B_ * N_;
        float4 v = reinterpret_cast<const float4*>(prefix + (size_t)r * DIM)[t];
        const int b = r >> 10, jr = r & 1023;
        uint2 raw;
        raw.x = (unsigned)f2bf(v.x) | ((unsigned)f2bf(v.y) << 16);
        raw.y = (unsigned)f2bf(v.z) | ((unsigned)f2bf(v.w) << 16);
        reinterpret_cast<uint2*>(kvin + ((size_t)b * J_ + jr) * DIM)[t] = raw;
    }
}

// ---------------- GEMM: C[M,N] f32 = A[M,K]bf16 * B[N,K]bf16^T ----------------
// tile 128(M)x64(N), BK=64, 4 waves in 2x2, each wave 64x32 (4x2 frags).
__global__ __launch_bounds__(256) void k_gemm_bt(
    const unsigned short* __restrict__ A, const unsigned short* __restrict__ Bm,
    float* __restrict__ C, int K, int ldc)
{
    __shared__ __align__(16) unsigned short As[128 * 64];
    __shared__ __align__(16) unsigned short Bs[64 * 64];
    const int tid = threadIdx.x;
    const int w = tid >> 6, lane = tid & 63;
    const int lg = lane >> 4, ll = lane & 15;
    const int m0 = blockIdx.y * 128, n0 = blockIdx.x * 64;
    const int wm = w >> 1, wn = w & 1;
    f32x4 acc[4][2];
    #pragma unroll
    for (int i = 0; i < 4; ++i)
        #pragma unroll
        for (int j = 0; j < 2; ++j)
            acc[i][j] = f32x4{0.f, 0.f, 0.f, 0.f};

    for (int k0 = 0; k0 < K; k0 += 64) {
        const unsigned short* Ab = A + (size_t)m0 * K + k0;
        const unsigned short* Bb = Bm + (size_t)n0 * K + k0;
        #pragma unroll
        for (int s = 0; s < 4; ++s) {
            int chunk = s * 256 + w * 64 + lane;
            int row = chunk >> 3, c = chunk & 7;
            int sc = (c ^ (row & 7)) * 8;
            gl_lds16(Ab + (size_t)row * K + sc, &As[chunk * 8]);
        }
        #pragma unroll
        for (int s = 0; s < 2; ++s) {
            int chunk = s * 256 + w * 64 + lane;
            int row = chunk >> 3, c = chunk & 7;
            int sc = (c ^ (row & 7)) * 8;
            gl_lds16(Bb + (size_t)row * K + sc, &Bs[chunk * 8]);
        }
        __syncthreads();
        bf16x8 af[4][2], bfr[2][2];
        #pragma unroll
        for (int ms = 0; ms < 4; ++ms) {
            #pragma unroll
            for (int ks = 0; ks < 2; ++ks) {
                int r = wm * 64 + ms * 16 + ll;
                int gc = ks * 4 + lg;
                af[ms][ks] = ld_bf16x8((const char*)As + r * 128 + ((gc ^ (r & 7)) << 4));
            }
        }
        #pragma unroll
        for (int ns = 0; ns < 2; ++ns) {
            #pragma unroll
            for (int ks = 0; ks < 2; ++ks) {
                int r = wn * 32 + ns * 16 + ll;
                int gc = ks * 4 + lg;
                bfr[ns][ks] = ld_bf16x8((const char*)Bs + r * 128 + ((gc ^ (r & 7)) << 4));
            }
        }
        #pragma unroll
        for (int ks = 0; ks < 2; ++ks)
            #pragma unroll
            for (int ms = 0; ms < 4; ++ms)
                #pragma unroll
                for (int ns = 0; ns < 2; ++ns)
                    acc[ms][ns] = __builtin_amdgcn_mfma_f32_16x16x32_bf16(
                        af[ms][ks], bfr[ns][ks], acc[ms][ns], 0, 0, 0);
        __syncthreads();
    }
    #pragma unroll
    for (int ms = 0; ms < 4; ++ms) {
        #pragma unroll
        for (int ns = 0; ns < 2; ++ns) {
            int col = n0 + wn * 32 + ns * 16 + ll;
            int rbase = m0 + wm * 64 + ms * 16 + lg * 4;
            #pragma unroll
            for (int rr = 0; rr < 4; ++rr)
                C[(size_t)(rbase + rr) * ldc + col] = acc[ms][ns][rr];
        }
    }
}

// ---------------- KV epilogue: K l2norm -> bf16 [B,J,DH]; V -> Vt bf16 [B,DH,J] ----------------
__global__ __launch_bounds__(256) void k_kv_epi(const float* __restrict__ KVg,
    const float* __restrict__ k_scale, unsigned short* __restrict__ Kb,
    unsigned short* __restrict__ Vt)
{
    __shared__ __align__(16) unsigned short Vs[64 * 64];
    const int blk = blockIdx.x;
    const int t = threadIdx.x;
    const int w = t >> 6, lane = t & 63;
    const int rowbase = blk * 64;
    const int b = rowbase >> 11;
    const int jloc = rowbase & 2047;
    float kscale = k_scale[lane];
    #pragma unroll
    for (int it = 0; it < 16; ++it) {
        int row = rowbase + w * 16 + it;
        float v = KVg[(size_t)row * 128 + lane];
        float ss = v * v;
        #pragma unroll
        for (int off = 32; off > 0; off >>= 1) ss += __shfl_xor(ss, off, 64);
        float inv = 1.0f / fmaxf(sqrtf(ss), 1e-12f);
        Kb[(size_t)row * DH + lane] = f2bf(v * inv * kscale);
    }
    const int r = t >> 2;
    const int cb = (t & 3) * 16;
    #pragma unroll
    for (int c4 = 0; c4 < 4; ++c4) {
        float4 v = *reinterpret_cast<const float4*>(&KVg[(size_t)(rowbase + r) * 128 + 64 + cb + c4 * 4]);
        Vs[(cb + c4 * 4 + 0) * 64 + r] = f2bf(v.x);
        Vs[(cb + c4 * 4 + 1) * 64 + r] = f2bf(v.y);
        Vs[(cb + c4 * 4 + 2) * 64 + r] = f2bf(v.z);
        Vs[(cb + c4 * 4 + 3) * 64 + r] = f2bf(v.w);
    }
    __syncthreads();
    const int d = t >> 2;
    const int jl = (t & 3) * 16;
    const int4* vsp = reinterpret_cast<const int4*>(&Vs[d * 64 + jl]);
    int4* dst = reinterpret_cast<int4*>(&Vt[((size_t)(b * 64 + d)) * J_ + jloc + jl]);
    dst[0] = vsp[0];
    dst[1] = vsp[1];
}

// ---------------- fused masked attention, S^T dataflow ----------------
// S^T = mfma(K, Q): each lane owns ONE q-row (ll) and 16 keys in-register.
// -> softmax reduce = 15 in-reg ops + 2 shuffles (was 32 shuffles)
// -> bias = 4 float4 loads (was 16 scalar loads)
// O^T = mfma(V^T, P^T): V^T frags = same vt loads; P^T via per-wave swizzled
// LDS roundtrip (4x 8B stores, 2x b128 reads). No __syncthreads anywhere.
__global__ __launch_bounds__(256) void k_attn(
    const float* __restrict__ Qg, const float* __restrict__ q_scale,
    const unsigned short* __restrict__ Kb, const unsigned short* __restrict__ Vt,
    const float* __restrict__ bias, unsigned short* __restrict__ AO)
{
    __shared__ __align__(16) unsigned short Ps[4][16 * 64];
    const int t = threadIdx.x, w = t >> 6, lane = t & 63;
    const int lg = lane >> 4, ll = lane & 15;
    const int qt = 15 - (blockIdx.x & 15);
    const int h = (blockIdx.x >> 4) & 15;
    const int b = blockIdx.x >> 8;
    const int qbase = qt * 64;
    const int qi = qbase + w * 16 + ll;   // this lane's q row (within N)
    const float NEG_INF = -__builtin_inff();

    bf16x8 qf[2];
    {
        const float* qrow = Qg + (size_t)(b * N_ + qi) * DIM + h * DH;
        float qv[16];
        #pragma unroll
        for (int ks = 0; ks < 2; ++ks) {
            float4 a = *reinterpret_cast<const float4*>(qrow + ks * 32 + lg * 8);
            float4 c = *reinterpret_cast<const float4*>(qrow + ks * 32 + lg * 8 + 4);
            qv[ks*8+0]=a.x; qv[ks*8+1]=a.y; qv[ks*8+2]=a.z; qv[ks*8+3]=a.w;
            qv[ks*8+4]=c.x; qv[ks*8+5]=c.y; qv[ks*8+6]=c.z; qv[ks*8+7]=c.w;
        }
        float ss = 0.f;
        #pragma unroll
        for (int j2 = 0; j2 < 16; ++j2) ss += qv[j2] * qv[j2];
        ss += __shfl_xor(ss, 16, 64);
        ss += __shfl_xor(ss, 32, 64);
        float inv = 1.0f / fmaxf(sqrtf(ss), 1e-12f);
        #pragma unroll
        for (int ks = 0; ks < 2; ++ks) {
            float4 s1 = *reinterpret_cast<const float4*>(q_scale + ks * 32 + lg * 8);
            float4 s2 = *reinterpret_cast<const float4*>(q_scale + ks * 32 + lg * 8 + 4);
            qv[ks*8+0] *= inv * s1.x; qv[ks*8+1] *= inv * s1.y;
            qv[ks*8+2] *= inv * s1.z; qv[ks*8+3] *= inv * s1.w;
            qv[ks*8+4] *= inv * s2.x; qv[ks*8+5] *= inv * s2.y;
            qv[ks*8+6] *= inv * s2.z; qv[ks*8+7] *= inv * s2.w;
        }
        qf[0] = packbf8(&qv[0]);
        qf[1] = packbf8(&qv[8]);
    }

    float m_run = -1e30f, l_run = 0.f;
    f32x4 o[4];
    #pragma unroll
    for (int ds = 0; ds < 4; ++ds) o[ds] = f32x4{0.f, 0.f, 0.f, 0.f};

    const unsigned short* Kbb = Kb + (size_t)b * J_ * DH;
    const unsigned short* Vbb = Vt + (size_t)b * 64 * J_;
    const float* bias_row = bias + ((size_t)h * N_ + qi) * N_;   // + j
    char* pbase = (char*)&Ps[w][0];
    const int swz = (ll & 7) << 4;

    const int npre = (qt > 0) ? 2 : 1;
    const int nt = npre + qt + 1;
    for (int idx = 0; idx < nt; ++idx) {
        const bool is_pre = idx < npre;
        const int tpre = (qt > 0) ? (qt - 1 + idx) : 0;
        const int kt = idx - npre;
        const int kvrow = is_pre ? tpre * 64 : P_ + kt * 64;
        const unsigned short* Kp = Kbb + (size_t)kvrow * DH;
        const unsigned short* Vp = Vbb + kvrow;

        // bias: 4x float4, per-lane consecutive keys (only causal tiles)
        f32x4 bb[4];
        if (!is_pre) {
            const float* bp = bias_row + kt * 64 + lg * 4;
            #pragma unroll
            for (int ns = 0; ns < 4; ++ns)
                bb[ns] = *reinterpret_cast<const f32x4*>(bp + ns * 16);
        }
        // K fragments (A-side: rows = keys)
        bf16x8 kf[4][2];
        #pragma unroll
        for (int ns = 0; ns < 4; ++ns)
            #pragma unroll
            for (int ks = 0; ks < 2; ++ks)
                kf[ns][ks] = ld_bf16x8(Kp + (size_t)(ns * 16 + ll) * DH + ks * 32 + lg * 8);
        // V^T fragments (A-side for PV: rows = d)
        bf16x8 vf[4][2];
        #pragma unroll
        for (int ds = 0; ds < 4; ++ds)
            #pragma unroll
            for (int ks = 0; ks < 2; ++ks)
                vf[ds][ks] = ld_bf16x8(Vp + (size_t)(ds * 16 + ll) * J_ + ks * 32 + lg * 8);

        // S^T = K · Q^T : lane holds q=ll, keys = ns*16 + lg*4 + rr
        f32x4 sv[4];
        __builtin_amdgcn_s_setprio(1);
        #pragma unroll
        for (int ns = 0; ns < 4; ++ns) {
            f32x4 s = f32x4{0.f, 0.f, 0.f, 0.f};
            #pragma unroll
            for (int ks = 0; ks < 2; ++ks)
                s = __builtin_amdgcn_mfma_f32_16x16x32_bf16(kf[ns][ks], qf[ks], s, 0, 0, 0);
            sv[ns] = s;
        }
        __builtin_amdgcn_s_setprio(0);

        // mask + bias
        #pragma unroll
        for (int ns = 0; ns < 4; ++ns) {
            #pragma unroll
            for (int rr = 0; rr < 4; ++rr) {
                int keyl = ns * 16 + lg * 4 + rr;
                float val = sv[ns][rr] * SCALE_;
                if (is_pre) {
                    int cc = kvrow + keyl;
                    bool ok = (qi >= cc) && (qi - cc < WIND);
                    val = ok ? val : NEG_INF;
                } else {
                    val += bb[ns][rr];
                    if (kt * 64 + keyl > qi) val = NEG_INF;
                }
                sv[ns][rr] = val;
            }
        }
        // row max: 16 in-reg + 2 shuffles
        float mx = sv[0][0];
        #pragma unroll
        for (int ns = 0; ns < 4; ++ns)
            #pragma unroll
            for (int rr = 0; rr < 4; ++rr) mx = fmaxf(mx, sv[ns][rr]);
        mx = fmaxf(mx, __shfl_xor(mx, 16, 64));
        mx = fmaxf(mx, __shfl_xor(mx, 32, 64));
        float mn = fmaxf(m_run, mx);
        float al = __expf(m_run - mn);
        m_run = mn;
        // exp + row sum
        float rs = 0.f;
        #pragma unroll
        for (int ns = 0; ns < 4; ++ns)
            #pragma unroll
            for (int rr = 0; rr < 4; ++rr) {
                float p = __expf(sv[ns][rr] - mn);
                sv[ns][rr] = p;
                rs += p;
            }
        rs += __shfl_xor(rs, 16, 64);
        rs += __shfl_xor(rs, 32, 64);
        l_run = l_run * al + rs;
        #pragma unroll
        for (int ds = 0; ds < 4; ++ds)
            #pragma unroll
            for (int rr = 0; rr < 4; ++rr)
                o[ds][rr] *= al;

        // P^T store: row = q (ll), 4 consecutive keys packed to 8B, swizzled
        #pragma unroll
        for (int ns = 0; ns < 4; ++ns) {
            uint2 pk;
            pk.x = (unsigned)f2bf(sv[ns][0]) | ((unsigned)f2bf(sv[ns][1]) << 16);
            pk.y = (unsigned)f2bf(sv[ns][2]) | ((unsigned)f2bf(sv[ns][3]) << 16);
            *reinterpret_cast<uint2*>(pbase + ll * 128 + ((ns * 32 + lg * 8) ^ swz)) = pk;
        }
        // P^T read as B-frag: lane = q (ll), 8 consecutive keys
        bf16x8 pf[2];
        #pragma unroll
        for (int ks = 0; ks < 2; ++ks)
            pf[ks] = ld_bf16x8(pbase + ll * 128 + ((ks * 64 + lg * 16) ^ swz));

        // O^T += V^T · P^T
        __builtin_amdgcn_s_setprio(1);
        #pragma unroll
        for (int ds = 0; ds < 4; ++ds)
            #pragma unroll
            for (int ks = 0; ks < 2; ++ks)
                o[ds] = __builtin_amdgcn_mfma_f32_16x16x32_bf16(vf[ds][ks], pf[ks], o[ds], 0, 0, 0);
        __builtin_amdgcn_s_setprio(0);
    }

    // epilogue: lane holds O^T[d = ds*16+lg*4+rr][q = ll]; 8B packed stores
    float inv = 1.0f / l_run;
    unsigned short* orow = AO + ((size_t)b * N_ + qi) * DIM + h * DH;
    #pragma unroll
    for (int ds = 0; ds < 4; ++ds) {
        uint2 pk;
        pk.x = (unsigned)f2bf(o[ds][0] * inv) | ((unsigned)f2bf(o[ds][1] * inv) << 16);
        pk.y = (unsigned)f2bf(o[ds][2] * inv) | ((unsigned)f2bf(o[ds][3] * inv) << 16);
        *reinterpret_cast<uint2*>(orow + ds * 16 + lg * 4) = pk;
    }
}

extern "C" void kernel_launch(void* const* d_in, const int* in_sizes, int n_in,
                              void* d_out, int out_size, void* d_ws, size_t ws_size,
                              hipStream_t stream)
{
    const float* x       = (const float*)d_in[0];
    const float* prefix  = (const float*)d_in[1];
    const float* bias    = (const float*)d_in[2];
    const float* gamma   = (const float*)d_in[3];
    const float* Wq      = (const float*)d_in[4];
    const float* Wkv     = (const float*)d_in[5];
    const float* q_scale = (const float*)d_in[6];
    const float* k_scale = (const float*)d_in[7];
    const float* Wo      = (const float*)d_in[8];
    float* out = (float*)d_out;

    char* ws = (char*)d_ws;
    unsigned short* xn   = (unsigned short*)(ws);              // 8 MB  [4096,1024] bf16
    unsigned short* kvin = (unsigned short*)(ws + 8388608);    // 16 MB [4,2048,1024] bf16
    unsigned short* wqb  = (unsigned short*)(ws + 25165824);   // 2 MB
    unsigned short* wkvb = (unsigned short*)(ws + 27262976);   // 256 KB
    unsigned short* wob  = (unsigned short*)(ws + 27525120);   // 2 MB
    float* qg            = (float*)(ws + 29622272);            // 16 MB [4096,1024] f32
    float* kvg           = (float*)(ws + 46399488);            // 4 MB  [8192,128] f32
    unsigned short* kb   = (unsigned short*)(ws + 58982400);   // 1 MB  [B,J,DH] bf16
    unsigned short* vt   = (unsigned short*)(ws + 60030976);   // 1 MB  [B,DH,J] bf16
    unsigned short* ao   = (unsigned short*)(ws + 61079552);   // 8 MB  [4096,1024] bf16

    k_cvt3<<<2176, 256, 0, stream>>>(Wq, Wkv, Wo, wqb, wkvb, wob);
    k_ln_cvt<<<8192, 256, 0, stream>>>(x, prefix, gamma, xn, kvin);
    k_gemm_bt<<<dim3(16, 32), 256, 0, stream>>>(xn, wqb, qg, 1024, 1024);
    k_gemm_bt<<<dim3(2, 64), 256, 0, stream>>>(kvin, wkvb, kvg, 1024, 128);
    k_kv_epi<<<128, 256, 0, stream>>>(kvg, k_scale, kb, vt);
    k_attn<<<1024, 256, 0, stream>>>(qg, q_scale, kb, vt, bias, ao);
    k_gemm_bt<<<dim3(16, 32), 256, 0, stream>>>(ao, wob, out, 1024, 1024);
}

// Round 6
// 329.370 us; speedup vs baseline: 1.4385x; 1.0730x over previous
//
#include <hip/hip_runtime.h>
#include <stdint.h>

#define DIM   1024
#define HEADS 16
#define DH    64
#define B_    4
#define N_    1024
#define P_    1024
#define J_    2048
#define SCALE_ 8.0f
#define WIND  16

typedef __attribute__((ext_vector_type(8))) short bf16x8;
typedef __attribute__((ext_vector_type(4))) float f32x4;

typedef __attribute__((address_space(1))) void* as1_t;
typedef __attribute__((address_space(3))) void* as3_t;

static __device__ __forceinline__ unsigned short f2bf(float f) {
    union { float f; unsigned u; } v; v.f = f;
    unsigned r = v.u + 0x7fffu + ((v.u >> 16) & 1u);
    return (unsigned short)(r >> 16);
}
static __device__ __forceinline__ bf16x8 ld_bf16x8(const void* p) {
    int4 v = *reinterpret_cast<const int4*>(p);
    return __builtin_bit_cast(bf16x8, v);
}
static __device__ __forceinline__ bf16x8 packbf8(const float* f) {
    bf16x8 r;
    #pragma unroll
    for (int j = 0; j < 8; ++j) r[j] = (short)f2bf(f[j]);
    return r;
}
static __device__ __forceinline__ void gl_lds16(const void* g, void* l) {
    __builtin_amdgcn_global_load_lds((as1_t)(size_t)g, (as3_t)l, 16, 0, 0);
}

// ---------------- f32 -> bf16 convert: all three weight matrices in one launch ----------------
__global__ __launch_bounds__(256) void k_cvt3(
    const float* __restrict__ wq, const float* __restrict__ wkv, const float* __restrict__ wo,
    unsigned short* __restrict__ dq, unsigned short* __restrict__ dkv, unsigned short* __restrict__ dwo)
{
    int i = blockIdx.x * 256 + threadIdx.x;
    const float* s; unsigned short* d; int off;
    if (i < 262144)      { s = wq;  d = dq;  off = i; }
    else if (i < 294912) { s = wkv; d = dkv; off = i - 262144; }
    else                 { s = wo;  d = dwo; off = i - 294912; }
    float4 v = reinterpret_cast<const float4*>(s)[off];
    uint2 o;
    o.x = (unsigned)f2bf(v.x) | ((unsigned)f2bf(v.y) << 16);
    o.y = (unsigned)f2bf(v.z) | ((unsigned)f2bf(v.w) << 16);
    reinterpret_cast<uint2*>(d)[off] = o;
}

// ---------------- LayerNorm(x) -> xn bf16 ; raw x,prefix -> kvin bf16 ----------------
__global__ __launch_bounds__(256) void k_ln_cvt(
    const float* __restrict__ x, const float* __restrict__ prefix,
    const float* __restrict__ gamma,
    unsigned short* __restrict__ xn, unsigned short* __restrict__ kvin)
{
    __shared__ float red[8];
    const int bid = blockIdx.x;
    const int t = threadIdx.x;
    const int w = t >> 6, lane = t & 63;
    if (bid < B_ * N_) {
        const int b = bid >> 10, n = bid & 1023;
        float4 v = reinterpret_cast<const float4*>(x + (size_t)bid * DIM)[t];
        uint2 raw;
        raw.x = (unsigned)f2bf(v.x) | ((unsigned)f2bf(v.y) << 16);
        raw.y = (unsigned)f2bf(v.z) | ((unsigned)f2bf(v.w) << 16);
        reinterpret_cast<uint2*>(kvin + ((size_t)b * J_ + P_ + n) * DIM)[t] = raw;
        float s = v.x + v.y + v.z + v.w;
        float ss = v.x*v.x + v.y*v.y + v.z*v.z + v.w*v.w;
        #pragma unroll
        for (int off = 32; off > 0; off >>= 1) {
            s  += __shfl_xor(s, off, 64);
            ss += __shfl_xor(ss, off, 64);
        }
        if (lane == 0) { red[w*2] = s; red[w*2+1] = ss; }
        __syncthreads();
        s  = red[0] + red[2] + red[4] + red[6];
        ss = red[1] + red[3] + red[5] + red[7];
        float mu = s * (1.0f / DIM);
        float var = ss * (1.0f / DIM) - mu * mu;
        float rs = rsqrtf(var + 1e-5f);
        float4 g = reinterpret_cast<const float4*>(gamma)[t];
        float o0 = (v.x - mu) * rs * g.x;
        float o1 = (v.y - mu) * rs * g.y;
        float o2 = (v.z - mu) * rs * g.z;
        float o3 = (v.w - mu) * rs * g.w;
        uint2 on;
        on.x = (unsigned)f2bf(o0) | ((unsigned)f2bf(o1) << 16);
        on.y = (unsigned)f2bf(o2) | ((unsigned)f2bf(o3) << 16);
        reinterpret_cast<uint2*>(xn + (size_t)bid * DIM)[t] = on;
    } else {
        const int r = bid - B_ * N_;
        float4 v = reinterpret_cast<const float4*>(prefix + (size_t)r * DIM)[t];
        const int b = r >> 10, jr = r & 1023;
        uint2 raw;
        raw.x = (unsigned)f2bf(v.x) | ((unsigned)f2bf(v.y) << 16);
        raw.y = (unsigned)f2bf(v.z) | ((unsigned)f2bf(v.w) << 16);
        reinterpret_cast<uint2*>(kvin + ((size_t)b * J_ + jr) * DIM)[t] = raw;
    }
}

// ---------------- GEMM: C[M,N] f32 = A[M,K]bf16 * B[N,K]bf16^T ----------------
// tile 128(M)x64(N), BK=64, 4 waves in 2x2, each wave 64x32 (4x2 frags).
__global__ __launch_bounds__(256) void k_gemm_bt(
    const unsigned short* __restrict__ A, const unsigned short* __restrict__ Bm,
    float* __restrict__ C, int K, int ldc)
{
    __shared__ __align__(16) unsigned short As[128 * 64];
    __shared__ __align__(16) unsigned short Bs[64 * 64];
    const int tid = threadIdx.x;
    const int w = tid >> 6, lane = tid & 63;
    const int lg = lane >> 4, ll = lane & 15;
    const int m0 = blockIdx.y * 128, n0 = blockIdx.x * 64;
    const int wm = w >> 1, wn = w & 1;
    f32x4 acc[4][2];
    #pragma unroll
    for (int i = 0; i < 4; ++i)
        #pragma unroll
        for (int j = 0; j < 2; ++j)
            acc[i][j] = f32x4{0.f, 0.f, 0.f, 0.f};

    for (int k0 = 0; k0 < K; k0 += 64) {
        const unsigned short* Ab = A + (size_t)m0 * K + k0;
        const unsigned short* Bb = Bm + (size_t)n0 * K + k0;
        #pragma unroll
        for (int s = 0; s < 4; ++s) {
            int chunk = s * 256 + w * 64 + lane;
            int row = chunk >> 3, c = chunk & 7;
            int sc = (c ^ (row & 7)) * 8;
            gl_lds16(Ab + (size_t)row * K + sc, &As[chunk * 8]);
        }
        #pragma unroll
        for (int s = 0; s < 2; ++s) {
            int chunk = s * 256 + w * 64 + lane;
            int row = chunk >> 3, c = chunk & 7;
            int sc = (c ^ (row & 7)) * 8;
            gl_lds16(Bb + (size_t)row * K + sc, &Bs[chunk * 8]);
        }
        __syncthreads();
        bf16x8 af[4][2], bfr[2][2];
        #pragma unroll
        for (int ms = 0; ms < 4; ++ms) {
            #pragma unroll
            for (int ks = 0; ks < 2; ++ks) {
                int r = wm * 64 + ms * 16 + ll;
                int gc = ks * 4 + lg;
                af[ms][ks] = ld_bf16x8((const char*)As + r * 128 + ((gc ^ (r & 7)) << 4));
            }
        }
        #pragma unroll
        for (int ns = 0; ns < 2; ++ns) {
            #pragma unroll
            for (int ks = 0; ks < 2; ++ks) {
                int r = wn * 32 + ns * 16 + ll;
                int gc = ks * 4 + lg;
                bfr[ns][ks] = ld_bf16x8((const char*)Bs + r * 128 + ((gc ^ (r & 7)) << 4));
            }
        }
        #pragma unroll
        for (int ks = 0; ks < 2; ++ks)
            #pragma unroll
            for (int ms = 0; ms < 4; ++ms)
                #pragma unroll
                for (int ns = 0; ns < 2; ++ns)
                    acc[ms][ns] = __builtin_amdgcn_mfma_f32_16x16x32_bf16(
                        af[ms][ks], bfr[ns][ks], acc[ms][ns], 0, 0, 0);
        __syncthreads();
    }
    #pragma unroll
    for (int ms = 0; ms < 4; ++ms) {
        #pragma unroll
        for (int ns = 0; ns < 2; ++ns) {
            int col = n0 + wn * 32 + ns * 16 + ll;
            int rbase = m0 + wm * 64 + ms * 16 + lg * 4;
            #pragma unroll
            for (int rr = 0; rr < 4; ++rr)
                C[(size_t)(rbase + rr) * ldc + col] = acc[ms][ns][rr];
        }
    }
}

// ---------------- KV epilogue: K l2norm -> bf16 [B,J,DH]; V -> Vt bf16 [B,DH,J] ----------------
__global__ __launch_bounds__(256) void k_kv_epi(const float* __restrict__ KVg,
    const float* __restrict__ k_scale, unsigned short* __restrict__ Kb,
    unsigned short* __restrict__ Vt)
{
    __shared__ __align__(16) unsigned short Vs[64 * 64];
    const int blk = blockIdx.x;
    const int t = threadIdx.x;
    const int w = t >> 6, lane = t & 63;
    const int rowbase = blk * 64;
    const int b = rowbase >> 11;
    const int jloc = rowbase & 2047;
    float kscale = k_scale[lane];
    #pragma unroll
    for (int it = 0; it < 16; ++it) {
        int row = rowbase + w * 16 + it;
        float v = KVg[(size_t)row * 128 + lane];
        float ss = v * v;
        #pragma unroll
        for (int off = 32; off > 0; off >>= 1) ss += __shfl_xor(ss, off, 64);
        float inv = 1.0f / fmaxf(sqrtf(ss), 1e-12f);
        Kb[(size_t)row * DH + lane] = f2bf(v * inv * kscale);
    }
    const int r = t >> 2;
    const int cb = (t & 3) * 16;
    #pragma unroll
    for (int c4 = 0; c4 < 4; ++c4) {
        float4 v = *reinterpret_cast<const float4*>(&KVg[(size_t)(rowbase + r) * 128 + 64 + cb + c4 * 4]);
        Vs[(cb + c4 * 4 + 0) * 64 + r] = f2bf(v.x);
        Vs[(cb + c4 * 4 + 1) * 64 + r] = f2bf(v.y);
        Vs[(cb + c4 * 4 + 2) * 64 + r] = f2bf(v.z);
        Vs[(cb + c4 * 4 + 3) * 64 + r] = f2bf(v.w);
    }
    __syncthreads();
    const int d = t >> 2;
    const int jl = (t & 3) * 16;
    const int4* vsp = reinterpret_cast<const int4*>(&Vs[d * 64 + jl]);
    int4* dst = reinterpret_cast<int4*>(&Vt[((size_t)(b * 64 + d)) * J_ + jloc + jl]);
    dst[0] = vsp[0];
    dst[1] = vsp[1];
}

// ---------------- fused masked attention, S^T dataflow, 1-wave blocks ----------------
// R5 post-mortem: VGPR_Count=80 forced the compiler to serialize the ~20 VMEM
// per tile into small batches, each paying a full L2/HBM round trip (~20K cy
// per tile measured). Fix: 1 wave per block, __launch_bounds__(64,3) -> VGPR
// cap 170 (live set ~140 fits), 12 waves/CU. All tile loads (bias HBM first,
// then K, then V) issue back-to-back and wait once.
__global__ __launch_bounds__(64, 3) void k_attn(
    const float* __restrict__ Qg, const float* __restrict__ q_scale,
    const unsigned short* __restrict__ Kb, const unsigned short* __restrict__ Vt,
    const float* __restrict__ bias, unsigned short* __restrict__ AO)
{
    __shared__ __align__(16) unsigned short Ps[16 * 64];
    const int lane = threadIdx.x & 63;
    const int lg = lane >> 4, ll = lane & 15;
    const int wsub = blockIdx.x & 3;
    const int qt = 15 - ((blockIdx.x >> 2) & 15);
    const int h = (blockIdx.x >> 6) & 15;
    const int b = blockIdx.x >> 10;
    const int qbase = qt * 64;
    const int qi = qbase + wsub * 16 + ll;   // this lane's q row (within N)
    const float NEG_INF = -__builtin_inff();

    bf16x8 qf[2];
    {
        const float* qrow = Qg + (size_t)(b * N_ + qi) * DIM + h * DH;
        float qv[16];
        #pragma unroll
        for (int ks = 0; ks < 2; ++ks) {
            float4 a = *reinterpret_cast<const float4*>(qrow + ks * 32 + lg * 8);
            float4 c = *reinterpret_cast<const float4*>(qrow + ks * 32 + lg * 8 + 4);
            qv[ks*8+0]=a.x; qv[ks*8+1]=a.y; qv[ks*8+2]=a.z; qv[ks*8+3]=a.w;
            qv[ks*8+4]=c.x; qv[ks*8+5]=c.y; qv[ks*8+6]=c.z; qv[ks*8+7]=c.w;
        }
        float ss = 0.f;
        #pragma unroll
        for (int j2 = 0; j2 < 16; ++j2) ss += qv[j2] * qv[j2];
        ss += __shfl_xor(ss, 16, 64);
        ss += __shfl_xor(ss, 32, 64);
        float inv = 1.0f / fmaxf(sqrtf(ss), 1e-12f);
        #pragma unroll
        for (int ks = 0; ks < 2; ++ks) {
            float4 s1 = *reinterpret_cast<const float4*>(q_scale + ks * 32 + lg * 8);
            float4 s2 = *reinterpret_cast<const float4*>(q_scale + ks * 32 + lg * 8 + 4);
            qv[ks*8+0] *= inv * s1.x; qv[ks*8+1] *= inv * s1.y;
            qv[ks*8+2] *= inv * s1.z; qv[ks*8+3] *= inv * s1.w;
            qv[ks*8+4] *= inv * s2.x; qv[ks*8+5] *= inv * s2.y;
            qv[ks*8+6] *= inv * s2.z; qv[ks*8+7] *= inv * s2.w;
        }
        qf[0] = packbf8(&qv[0]);
        qf[1] = packbf8(&qv[8]);
    }

    float m_run = -1e30f, l_run = 0.f;
    f32x4 o[4];
    #pragma unroll
    for (int ds = 0; ds < 4; ++ds) o[ds] = f32x4{0.f, 0.f, 0.f, 0.f};

    const unsigned short* Kbb = Kb + (size_t)b * J_ * DH;
    const unsigned short* Vbb = Vt + (size_t)b * 64 * J_;
    const float* bias_row = bias + ((size_t)h * N_ + qi) * N_;   // + j
    char* pbase = (char*)&Ps[0];
    const int swz = (ll & 7) << 4;

    const int npre = (qt > 0) ? 2 : 1;
    const int nt = npre + qt + 1;
    for (int idx = 0; idx < nt; ++idx) {
        const bool is_pre = idx < npre;
        const int tpre = (qt > 0) ? (qt - 1 + idx) : 0;
        const int kt = idx - npre;
        const int kvrow = is_pre ? tpre * 64 : P_ + kt * 64;
        const unsigned short* Kp = Kbb + (size_t)kvrow * DH;
        const unsigned short* Vp = Vbb + kvrow;

        // bias first (HBM, longest latency): 4x float4, per-lane consecutive keys
        f32x4 bb[4];
        if (!is_pre) {
            const float* bp = bias_row + kt * 64 + lg * 4;
            #pragma unroll
            for (int ns = 0; ns < 4; ++ns)
                bb[ns] = *reinterpret_cast<const f32x4*>(bp + ns * 16);
        }
        // K fragments (A-side: rows = keys)
        bf16x8 kf[4][2];
        #pragma unroll
        for (int ns = 0; ns < 4; ++ns)
            #pragma unroll
            for (int ks = 0; ks < 2; ++ks)
                kf[ns][ks] = ld_bf16x8(Kp + (size_t)(ns * 16 + ll) * DH + ks * 32 + lg * 8);
        // V^T fragments (A-side for PV: rows = d)
        bf16x8 vf[4][2];
        #pragma unroll
        for (int ds = 0; ds < 4; ++ds)
            #pragma unroll
            for (int ks = 0; ks < 2; ++ks)
                vf[ds][ks] = ld_bf16x8(Vp + (size_t)(ds * 16 + ll) * J_ + ks * 32 + lg * 8);

        // S^T = K · Q^T : lane holds q=ll, keys = ns*16 + lg*4 + rr
        f32x4 sv[4];
        __builtin_amdgcn_s_setprio(1);
        #pragma unroll
        for (int ns = 0; ns < 4; ++ns) {
            f32x4 s = f32x4{0.f, 0.f, 0.f, 0.f};
            #pragma unroll
            for (int ks = 0; ks < 2; ++ks)
                s = __builtin_amdgcn_mfma_f32_16x16x32_bf16(kf[ns][ks], qf[ks], s, 0, 0, 0);
            sv[ns] = s;
        }
        __builtin_amdgcn_s_setprio(0);

        // mask + bias
        #pragma unroll
        for (int ns = 0; ns < 4; ++ns) {
            #pragma unroll
            for (int rr = 0; rr < 4; ++rr) {
                int keyl = ns * 16 + lg * 4 + rr;
                float val = sv[ns][rr] * SCALE_;
                if (is_pre) {
                    int cc = kvrow + keyl;
                    bool ok = (qi >= cc) && (qi - cc < WIND);
                    val = ok ? val : NEG_INF;
                } else {
                    val += bb[ns][rr];
                    if (kt * 64 + keyl > qi) val = NEG_INF;
                }
                sv[ns][rr] = val;
            }
        }
        // row max: 16 in-reg + 2 shuffles
        float mx = sv[0][0];
        #pragma unroll
        for (int ns = 0; ns < 4; ++ns)
            #pragma unroll
            for (int rr = 0; rr < 4; ++rr) mx = fmaxf(mx, sv[ns][rr]);
        mx = fmaxf(mx, __shfl_xor(mx, 16, 64));
        mx = fmaxf(mx, __shfl_xor(mx, 32, 64));
        float mn = fmaxf(m_run, mx);
        float al = __expf(m_run - mn);
        m_run = mn;
        // exp + row sum
        float rs = 0.f;
        #pragma unroll
        for (int ns = 0; ns < 4; ++ns)
            #pragma unroll
            for (int rr = 0; rr < 4; ++rr) {
                float p = __expf(sv[ns][rr] - mn);
                sv[ns][rr] = p;
                rs += p;
            }
        rs += __shfl_xor(rs, 16, 64);
        rs += __shfl_xor(rs, 32, 64);
        l_run = l_run * al + rs;
        #pragma unroll
        for (int ds = 0; ds < 4; ++ds)
            #pragma unroll
            for (int rr = 0; rr < 4; ++rr)
                o[ds][rr] *= al;

        // P^T store: row = q (ll), 4 consecutive keys packed to 8B, swizzled
        #pragma unroll
        for (int ns = 0; ns < 4; ++ns) {
            uint2 pk;
            pk.x = (unsigned)f2bf(sv[ns][0]) | ((unsigned)f2bf(sv[ns][1]) << 16);
            pk.y = (unsigned)f2bf(sv[ns][2]) | ((unsigned)f2bf(sv[ns][3]) << 16);
            *reinterpret_cast<uint2*>(pbase + ll * 128 + ((ns * 32 + lg * 8) ^ swz)) = pk;
        }
        // P^T read as B-frag: lane = q (ll), 8 consecutive keys
        bf16x8 pf[2];
        #pragma unroll
        for (int ks = 0; ks < 2; ++ks)
            pf[ks] = ld_bf16x8(pbase + ll * 128 + ((ks * 64 + lg * 16) ^ swz));

        // O^T += V^T · P^T
        __builtin_amdgcn_s_setprio(1);
        #pragma unroll
        for (int ds = 0; ds < 4; ++ds)
            #pragma unroll
            for (int ks = 0; ks < 2; ++ks)
                o[ds] = __builtin_amdgcn_mfma_f32_16x16x32_bf16(vf[ds][ks], pf[ks], o[ds], 0, 0, 0);
        __builtin_amdgcn_s_setprio(0);
    }

    // epilogue: lane holds O^T[d = ds*16+lg*4+rr][q = ll]; 8B packed stores
    float inv = 1.0f / l_run;
    unsigned short* orow = AO + ((size_t)b * N_ + qi) * DIM + h * DH;
    #pragma unroll
    for (int ds = 0; ds < 4; ++ds) {
        uint2 pk;
        pk.x = (unsigned)f2bf(o[ds][0] * inv) | ((unsigned)f2bf(o[ds][1] * inv) << 16);
        pk.y = (unsigned)f2bf(o[ds][2] * inv) | ((unsigned)f2bf(o[ds][3] * inv) << 16);
        *reinterpret_cast<uint2*>(orow + ds * 16 + lg * 4) = pk;
    }
}

extern "C" void kernel_launch(void* const* d_in, const int* in_sizes, int n_in,
                              void* d_out, int out_size, void* d_ws, size_t ws_size,
                              hipStream_t stream)
{
    const float* x       = (const float*)d_in[0];
    const float* prefix  = (const float*)d_in[1];
    const float* bias    = (const float*)d_in[2];
    const float* gamma   = (const float*)d_in[3];
    const float* Wq      = (const float*)d_in[4];
    const float* Wkv     = (const float*)d_in[5];
    const float* q_scale = (const float*)d_in[6];
    const float* k_scale = (const float*)d_in[7];
    const float* Wo      = (const float*)d_in[8];
    float* out = (float*)d_out;

    char* ws = (char*)d_ws;
    unsigned short* xn   = (unsigned short*)(ws);              // 8 MB  [4096,1024] bf16
    unsigned short* kvin = (unsigned short*)(ws + 8388608);    // 16 MB [4,2048,1024] bf16
    unsigned short* wqb  = (unsigned short*)(ws + 25165824);   // 2 MB
    unsigned short* wkvb = (unsigned short*)(ws + 27262976);   // 256 KB
    unsigned short* wob  = (unsigned short*)(ws + 27525120);   // 2 MB
    float* qg            = (float*)(ws + 29622272);            // 16 MB [4096,1024] f32
    float* kvg           = (float*)(ws + 46399488);            // 4 MB  [8192,128] f32
    unsigned short* kb   = (unsigned short*)(ws + 58982400);   // 1 MB  [B,J,DH] bf16
    unsigned short* vt   = (unsigned short*)(ws + 60030976);   // 1 MB  [B,DH,J] bf16
    unsigned short* ao   = (unsigned short*)(ws + 61079552);   // 8 MB  [4096,1024] bf16

    k_cvt3<<<2176, 256, 0, stream>>>(Wq, Wkv, Wo, wqb, wkvb, wob);
    k_ln_cvt<<<8192, 256, 0, stream>>>(x, prefix, gamma, xn, kvin);
    k_gemm_bt<<<dim3(16, 32), 256, 0, stream>>>(xn, wqb, qg, 1024, 1024);
    k_gemm_bt<<<dim3(2, 64), 256, 0, stream>>>(kvin, wkvb, kvg, 1024, 128);
    k_kv_epi<<<128, 256, 0, stream>>>(kvg, k_scale, kb, vt);
    k_attn<<<4096, 64, 0, stream>>>(qg, q_scale, kb, vt, bias, ao);
    k_gemm_bt<<<dim3(16, 32), 256, 0, stream>>>(ao, wob, out, 1024, 1024);
}

// Round 8
// 294.791 us; speedup vs baseline: 1.6073x; 1.1173x over previous
//
#include <hip/hip_runtime.h>
#include <stdint.h>

#define DIM   1024
#define HEADS 16
#define DH    64
#define B_    4
#define N_    1024
#define P_    1024
#define J_    2048
#define SCALE_ 8.0f
#define WIND  16

typedef __attribute__((ext_vector_type(8))) short bf16x8;
typedef __attribute__((ext_vector_type(4))) float f32x4;

typedef __attribute__((address_space(1))) void* as1_t;
typedef __attribute__((address_space(3))) void* as3_t;

static __device__ __forceinline__ unsigned short f2bf(float f) {
    union { float f; unsigned u; } v; v.f = f;
    unsigned r = v.u + 0x7fffu + ((v.u >> 16) & 1u);
    return (unsigned short)(r >> 16);
}
static __device__ __forceinline__ bf16x8 ld_bf16x8(const void* p) {
    int4 v = *reinterpret_cast<const int4*>(p);
    return __builtin_bit_cast(bf16x8, v);
}
static __device__ __forceinline__ bf16x8 packbf8(const float* f) {
    bf16x8 r;
    #pragma unroll
    for (int j = 0; j < 8; ++j) r[j] = (short)f2bf(f[j]);
    return r;
}
static __device__ __forceinline__ void gl_lds16(const void* g, void* l) {
    __builtin_amdgcn_global_load_lds((as1_t)(size_t)g, (as3_t)l, 16, 0, 0);
}

// ---------------- f32 -> bf16 convert: all three weight matrices in one launch ----------------
__global__ __launch_bounds__(256) void k_cvt3(
    const float* __restrict__ wq, const float* __restrict__ wkv, const float* __restrict__ wo,
    unsigned short* __restrict__ dq, unsigned short* __restrict__ dkv, unsigned short* __restrict__ dwo)
{
    int i = blockIdx.x * 256 + threadIdx.x;
    const float* s; unsigned short* d; int off;
    if (i < 262144)      { s = wq;  d = dq;  off = i; }
    else if (i < 294912) { s = wkv; d = dkv; off = i - 262144; }
    else                 { s = wo;  d = dwo; off = i - 294912; }
    float4 v = reinterpret_cast<const float4*>(s)[off];
    uint2 o;
    o.x = (unsigned)f2bf(v.x) | ((unsigned)f2bf(v.y) << 16);
    o.y = (unsigned)f2bf(v.z) | ((unsigned)f2bf(v.w) << 16);
    reinterpret_cast<uint2*>(d)[off] = o;
}

// ---------------- LayerNorm(x) -> xn bf16 ; raw x,prefix -> kvin bf16 ----------------
__global__ __launch_bounds__(256) void k_ln_cvt(
    const float* __restrict__ x, const float* __restrict__ prefix,
    const float* __restrict__ gamma,
    unsigned short* __restrict__ xn, unsigned short* __restrict__ kvin)
{
    __shared__ float red[8];
    const int bid = blockIdx.x;
    const int t = threadIdx.x;
    const int w = t >> 6, lane = t & 63;
    if (bid < B_ * N_) {
        const int b = bid >> 10, n = bid & 1023;
        float4 v = reinterpret_cast<const float4*>(x + (size_t)bid * DIM)[t];
        uint2 raw;
        raw.x = (unsigned)f2bf(v.x) | ((unsigned)f2bf(v.y) << 16);
        raw.y = (unsigned)f2bf(v.z) | ((unsigned)f2bf(v.w) << 16);
        reinterpret_cast<uint2*>(kvin + ((size_t)b * J_ + P_ + n) * DIM)[t] = raw;
        float s = v.x + v.y + v.z + v.w;
        float ss = v.x*v.x + v.y*v.y + v.z*v.z + v.w*v.w;
        #pragma unroll
        for (int off = 32; off > 0; off >>= 1) {
            s  += __shfl_xor(s, off, 64);
            ss += __shfl_xor(ss, off, 64);
        }
        if (lane == 0) { red[w*2] = s; red[w*2+1] = ss; }
        __syncthreads();
        s  = red[0] + red[2] + red[4] + red[6];
        ss = red[1] + red[3] + red[5] + red[7];
        float mu = s * (1.0f / DIM);
        float var = ss * (1.0f / DIM) - mu * mu;
        float rs = rsqrtf(var + 1e-5f);
        float4 g = reinterpret_cast<const float4*>(gamma)[t];
        float o0 = (v.x - mu) * rs * g.x;
        float o1 = (v.y - mu) * rs * g.y;
        float o2 = (v.z - mu) * rs * g.z;
        float o3 = (v.w - mu) * rs * g.w;
        uint2 on;
        on.x = (unsigned)f2bf(o0) | ((unsigned)f2bf(o1) << 16);
        on.y = (unsigned)f2bf(o2) | ((unsigned)f2bf(o3) << 16);
        reinterpret_cast<uint2*>(xn + (size_t)bid * DIM)[t] = on;
    } else {
        const int r = bid - B_ * N_;
        float4 v = reinterpret_cast<const float4*>(prefix + (size_t)r * DIM)[t];
        const int b = r >> 10, jr = r & 1023;
        uint2 raw;
        raw.x = (unsigned)f2bf(v.x) | ((unsigned)f2bf(v.y) << 16);
        raw.y = (unsigned)f2bf(v.z) | ((unsigned)f2bf(v.w) << 16);
        reinterpret_cast<uint2*>(kvin + ((size_t)b * J_ + jr) * DIM)[t] = raw;
    }
}

// ---------------- GEMM: C[M,N] f32 = A[M,K]bf16 * B[N,K]bf16^T ----------------
// tile 128(M)x64(N), BK=64, 4 waves in 2x2, each wave 64x32 (4x2 frags).
__global__ __launch_bounds__(256) void k_gemm_bt(
    const unsigned short* __restrict__ A, const unsigned short* __restrict__ Bm,
    float* __restrict__ C, int K, int ldc)
{
    __shared__ __align__(16) unsigned short As[128 * 64];
    __shared__ __align__(16) unsigned short Bs[64 * 64];
    const int tid = threadIdx.x;
    const int w = tid >> 6, lane = tid & 63;
    const int lg = lane >> 4, ll = lane & 15;
    const int m0 = blockIdx.y * 128, n0 = blockIdx.x * 64;
    const int wm = w >> 1, wn = w & 1;
    f32x4 acc[4][2];
    #pragma unroll
    for (int i = 0; i < 4; ++i)
        #pragma unroll
        for (int j = 0; j < 2; ++j)
            acc[i][j] = f32x4{0.f, 0.f, 0.f, 0.f};

    for (int k0 = 0; k0 < K; k0 += 64) {
        const unsigned short* Ab = A + (size_t)m0 * K + k0;
        const unsigned short* Bb = Bm + (size_t)n0 * K + k0;
        #pragma unroll
        for (int s = 0; s < 4; ++s) {
            int chunk = s * 256 + w * 64 + lane;
            int row = chunk >> 3, c = chunk & 7;
            int sc = (c ^ (row & 7)) * 8;
            gl_lds16(Ab + (size_t)row * K + sc, &As[chunk * 8]);
        }
        #pragma unroll
        for (int s = 0; s < 2; ++s) {
            int chunk = s * 256 + w * 64 + lane;
            int row = chunk >> 3, c = chunk & 7;
            int sc = (c ^ (row & 7)) * 8;
            gl_lds16(Bb + (size_t)row * K + sc, &Bs[chunk * 8]);
        }
        __syncthreads();
        bf16x8 af[4][2], bfr[2][2];
        #pragma unroll
        for (int ms = 0; ms < 4; ++ms) {
            #pragma unroll
            for (int ks = 0; ks < 2; ++ks) {
                int r = wm * 64 + ms * 16 + ll;
                int gc = ks * 4 + lg;
                af[ms][ks] = ld_bf16x8((const char*)As + r * 128 + ((gc ^ (r & 7)) << 4));
            }
        }
        #pragma unroll
        for (int ns = 0; ns < 2; ++ns) {
            #pragma unroll
            for (int ks = 0; ks < 2; ++ks) {
                int r = wn * 32 + ns * 16 + ll;
                int gc = ks * 4 + lg;
                bfr[ns][ks] = ld_bf16x8((const char*)Bs + r * 128 + ((gc ^ (r & 7)) << 4));
            }
        }
        #pragma unroll
        for (int ks = 0; ks < 2; ++ks)
            #pragma unroll
            for (int ms = 0; ms < 4; ++ms)
                #pragma unroll
                for (int ns = 0; ns < 2; ++ns)
                    acc[ms][ns] = __builtin_amdgcn_mfma_f32_16x16x32_bf16(
                        af[ms][ks], bfr[ns][ks], acc[ms][ns], 0, 0, 0);
        __syncthreads();
    }
    #pragma unroll
    for (int ms = 0; ms < 4; ++ms) {
        #pragma unroll
        for (int ns = 0; ns < 2; ++ns) {
            int col = n0 + wn * 32 + ns * 16 + ll;
            int rbase = m0 + wm * 64 + ms * 16 + lg * 4;
            #pragma unroll
            for (int rr = 0; rr < 4; ++rr)
                C[(size_t)(rbase + rr) * ldc + col] = acc[ms][ns][rr];
        }
    }
}

// ---------------- KV epilogue: K l2norm -> bf16 [B,J,DH]; V -> Vt bf16 [B,DH,J] ----------------
__global__ __launch_bounds__(256) void k_kv_epi(const float* __restrict__ KVg,
    const float* __restrict__ k_scale, unsigned short* __restrict__ Kb,
    unsigned short* __restrict__ Vt)
{
    __shared__ __align__(16) unsigned short Vs[64 * 64];
    const int blk = blockIdx.x;
    const int t = threadIdx.x;
    const int w = t >> 6, lane = t & 63;
    const int rowbase = blk * 64;
    const int b = rowbase >> 11;
    const int jloc = rowbase & 2047;
    float kscale = k_scale[lane];
    #pragma unroll
    for (int it = 0; it < 16; ++it) {
        int row = rowbase + w * 16 + it;
        float v = KVg[(size_t)row * 128 + lane];
        float ss = v * v;
        #pragma unroll
        for (int off = 32; off > 0; off >>= 1) ss += __shfl_xor(ss, off, 64);
        float inv = 1.0f / fmaxf(sqrtf(ss), 1e-12f);
        Kb[(size_t)row * DH + lane] = f2bf(v * inv * kscale);
    }
    const int r = t >> 2;
    const int cb = (t & 3) * 16;
    #pragma unroll
    for (int c4 = 0; c4 < 4; ++c4) {
        float4 v = *reinterpret_cast<const float4*>(&KVg[(size_t)(rowbase + r) * 128 + 64 + cb + c4 * 4]);
        Vs[(cb + c4 * 4 + 0) * 64 + r] = f2bf(v.x);
        Vs[(cb + c4 * 4 + 1) * 64 + r] = f2bf(v.y);
        Vs[(cb + c4 * 4 + 2) * 64 + r] = f2bf(v.z);
        Vs[(cb + c4 * 4 + 3) * 64 + r] = f2bf(v.w);
    }
    __syncthreads();
    const int d = t >> 2;
    const int jl = (t & 3) * 16;
    const int4* vsp = reinterpret_cast<const int4*>(&Vs[d * 64 + jl]);
    int4* dst = reinterpret_cast<int4*>(&Vt[((size_t)(b * 64 + d)) * J_ + jloc + jl]);
    dst[0] = vsp[0];
    dst[1] = vsp[1];
}

// ---------------- fused masked attention, S^T dataflow, 1-wave blocks ----------------
// R6 post-mortem: blockIdx low 8 bits repeated with period 256 (=#CUs), so
// round-robin dispatch gave each CU ONLY blocks of one qt length -> 2x load
// imbalance + long idle tail (Occupancy 18%, nothing >20% busy). Fix: qt in
// the HIGH bits: blockIdx = qtp*256 + h*16 + b*4 + wsub. Each CU's stride-256
// samples now cover every qt level exactly once (167 tiles/CU, balanced),
// dispatch order still longest-first.
__global__ __launch_bounds__(64, 3) void k_attn(
    const float* __restrict__ Qg, const float* __restrict__ q_scale,
    const unsigned short* __restrict__ Kb, const unsigned short* __restrict__ Vt,
    const float* __restrict__ bias, unsigned short* __restrict__ AO)
{
    __shared__ __align__(16) unsigned short Ps[16 * 64];
    const int lane = threadIdx.x & 63;
    const int lg = lane >> 4, ll = lane & 15;
    const int wsub = blockIdx.x & 3;
    const int b = (blockIdx.x >> 2) & 3;
    const int h = (blockIdx.x >> 4) & 15;
    const int qt = 15 - ((blockIdx.x >> 8) & 15);
    const int qbase = qt * 64;
    const int qi = qbase + wsub * 16 + ll;   // this lane's q row (within N)
    const float NEG_INF = -__builtin_inff();

    bf16x8 qf[2];
    {
        const float* qrow = Qg + (size_t)(b * N_ + qi) * DIM + h * DH;
        float qv[16];
        #pragma unroll
        for (int ks = 0; ks < 2; ++ks) {
            float4 a = *reinterpret_cast<const float4*>(qrow + ks * 32 + lg * 8);
            float4 c = *reinterpret_cast<const float4*>(qrow + ks * 32 + lg * 8 + 4);
            qv[ks*8+0]=a.x; qv[ks*8+1]=a.y; qv[ks*8+2]=a.z; qv[ks*8+3]=a.w;
            qv[ks*8+4]=c.x; qv[ks*8+5]=c.y; qv[ks*8+6]=c.z; qv[ks*8+7]=c.w;
        }
        float ss = 0.f;
        #pragma unroll
        for (int j2 = 0; j2 < 16; ++j2) ss += qv[j2] * qv[j2];
        ss += __shfl_xor(ss, 16, 64);
        ss += __shfl_xor(ss, 32, 64);
        float inv = 1.0f / fmaxf(sqrtf(ss), 1e-12f);
        #pragma unroll
        for (int ks = 0; ks < 2; ++ks) {
            float4 s1 = *reinterpret_cast<const float4*>(q_scale + ks * 32 + lg * 8);
            float4 s2 = *reinterpret_cast<const float4*>(q_scale + ks * 32 + lg * 8 + 4);
            qv[ks*8+0] *= inv * s1.x; qv[ks*8+1] *= inv * s1.y;
            qv[ks*8+2] *= inv * s1.z; qv[ks*8+3] *= inv * s1.w;
            qv[ks*8+4] *= inv * s2.x; qv[ks*8+5] *= inv * s2.y;
            qv[ks*8+6] *= inv * s2.z; qv[ks*8+7] *= inv * s2.w;
        }
        qf[0] = packbf8(&qv[0]);
        qf[1] = packbf8(&qv[8]);
    }

    float m_run = -1e30f, l_run = 0.f;
    f32x4 o[4];
    #pragma unroll
    for (int ds = 0; ds < 4; ++ds) o[ds] = f32x4{0.f, 0.f, 0.f, 0.f};

    const unsigned short* Kbb = Kb + (size_t)b * J_ * DH;
    const unsigned short* Vbb = Vt + (size_t)b * 64 * J_;
    const float* bias_row = bias + ((size_t)h * N_ + qi) * N_;   // + j
    char* pbase = (char*)&Ps[0];
    const int swz = (ll & 7) << 4;

    const int npre = (qt > 0) ? 2 : 1;
    const int nt = npre + qt + 1;
    for (int idx = 0; idx < nt; ++idx) {
        const bool is_pre = idx < npre;
        const int tpre = (qt > 0) ? (qt - 1 + idx) : 0;
        const int kt = idx - npre;
        const int kvrow = is_pre ? tpre * 64 : P_ + kt * 64;
        const unsigned short* Kp = Kbb + (size_t)kvrow * DH;
        const unsigned short* Vp = Vbb + kvrow;

        // bias first (HBM, longest latency): 4x float4, per-lane consecutive keys
        f32x4 bb[4];
        if (!is_pre) {
            const float* bp = bias_row + kt * 64 + lg * 4;
            #pragma unroll
            for (int ns = 0; ns < 4; ++ns)
                bb[ns] = *reinterpret_cast<const f32x4*>(bp + ns * 16);
        }
        // K fragments (A-side: rows = keys)
        bf16x8 kf[4][2];
        #pragma unroll
        for (int ns = 0; ns < 4; ++ns)
            #pragma unroll
            for (int ks = 0; ks < 2; ++ks)
                kf[ns][ks] = ld_bf16x8(Kp + (size_t)(ns * 16 + ll) * DH + ks * 32 + lg * 8);
        // V^T fragments (A-side for PV: rows = d)
        bf16x8 vf[4][2];
        #pragma unroll
        for (int ds = 0; ds < 4; ++ds)
            #pragma unroll
            for (int ks = 0; ks < 2; ++ks)
                vf[ds][ks] = ld_bf16x8(Vp + (size_t)(ds * 16 + ll) * J_ + ks * 32 + lg * 8);

        // S^T = K · Q^T : lane holds q=ll, keys = ns*16 + lg*4 + rr
        f32x4 sv[4];
        __builtin_amdgcn_s_setprio(1);
        #pragma unroll
        for (int ns = 0; ns < 4; ++ns) {
            f32x4 s = f32x4{0.f, 0.f, 0.f, 0.f};
            #pragma unroll
            for (int ks = 0; ks < 2; ++ks)
                s = __builtin_amdgcn_mfma_f32_16x16x32_bf16(kf[ns][ks], qf[ks], s, 0, 0, 0);
            sv[ns] = s;
        }
        __builtin_amdgcn_s_setprio(0);

        // mask + bias
        #pragma unroll
        for (int ns = 0; ns < 4; ++ns) {
            #pragma unroll
            for (int rr = 0; rr < 4; ++rr) {
                int keyl = ns * 16 + lg * 4 + rr;
                float val = sv[ns][rr] * SCALE_;
                if (is_pre) {
                    int cc = kvrow + keyl;
                    bool ok = (qi >= cc) && (qi - cc < WIND);
                    val = ok ? val : NEG_INF;
                } else {
                    val += bb[ns][rr];
                    if (kt * 64 + keyl > qi) val = NEG_INF;
                }
                sv[ns][rr] = val;
            }
        }
        // row max: 16 in-reg + 2 shuffles
        float mx = sv[0][0];
        #pragma unroll
        for (int ns = 0; ns < 4; ++ns)
            #pragma unroll
            for (int rr = 0; rr < 4; ++rr) mx = fmaxf(mx, sv[ns][rr]);
        mx = fmaxf(mx, __shfl_xor(mx, 16, 64));
        mx = fmaxf(mx, __shfl_xor(mx, 32, 64));
        float mn = fmaxf(m_run, mx);
        float al = __expf(m_run - mn);
        m_run = mn;
        // exp + row sum
        float rs = 0.f;
        #pragma unroll
        for (int ns = 0; ns < 4; ++ns)
            #pragma unroll
            for (int rr = 0; rr < 4; ++rr) {
                float p = __expf(sv[ns][rr] - mn);
                sv[ns][rr] = p;
                rs += p;
            }
        rs += __shfl_xor(rs, 16, 64);
        rs += __shfl_xor(rs, 32, 64);
        l_run = l_run * al + rs;
        #pragma unroll
        for (int ds = 0; ds < 4; ++ds)
            #pragma unroll
            for (int rr = 0; rr < 4; ++rr)
                o[ds][rr] *= al;

        // P^T store: row = q (ll), 4 consecutive keys packed to 8B, swizzled
        #pragma unroll
        for (int ns = 0; ns < 4; ++ns) {
            uint2 pk;
            pk.x = (unsigned)f2bf(sv[ns][0]) | ((unsigned)f2bf(sv[ns][1]) << 16);
            pk.y = (unsigned)f2bf(sv[ns][2]) | ((unsigned)f2bf(sv[ns][3]) << 16);
            *reinterpret_cast<uint2*>(pbase + ll * 128 + ((ns * 32 + lg * 8) ^ swz)) = pk;
        }
        // P^T read as B-frag: lane = q (ll), 8 consecutive keys
        bf16x8 pf[2];
        #pragma unroll
        for (int ks = 0; ks < 2; ++ks)
            pf[ks] = ld_bf16x8(pbase + ll * 128 + ((ks * 64 + lg * 16) ^ swz));

        // O^T += V^T · P^T
        __builtin_amdgcn_s_setprio(1);
        #pragma unroll
        for (int ds = 0; ds < 4; ++ds)
            #pragma unroll
            for (int ks = 0; ks < 2; ++ks)
                o[ds] = __builtin_amdgcn_mfma_f32_16x16x32_bf16(vf[ds][ks], pf[ks], o[ds], 0, 0, 0);
        __builtin_amdgcn_s_setprio(0);
    }

    // epilogue: lane holds O^T[d = ds*16+lg*4+rr][q = ll]; 8B packed stores
    float inv = 1.0f / l_run;
    unsigned short* orow = AO + ((size_t)b * N_ + qi) * DIM + h * DH;
    #pragma unroll
    for (int ds = 0; ds < 4; ++ds) {
        uint2 pk;
        pk.x = (unsigned)f2bf(o[ds][0] * inv) | ((unsigned)f2bf(o[ds][1] * inv) << 16);
        pk.y = (unsigned)f2bf(o[ds][2] * inv) | ((unsigned)f2bf(o[ds][3] * inv) << 16);
        *reinterpret_cast<uint2*>(orow + ds * 16 + lg * 4) = pk;
    }
}

extern "C" void kernel_launch(void* const* d_in, const int* in_sizes, int n_in,
                              void* d_out, int out_size, void* d_ws, size_t ws_size,
                              hipStream_t stream)
{
    const float* x       = (const float*)d_in[0];
    const float* prefix  = (const float*)d_in[1];
    const float* bias    = (const float*)d_in[2];
    const float* gamma   = (const float*)d_in[3];
    const float* Wq      = (const float*)d_in[4];
    const float* Wkv     = (const float*)d_in[5];
    const float* q_scale = (const float*)d_in[6];
    const float* k_scale = (const float*)d_in[7];
    const float* Wo      = (const float*)d_in[8];
    float* out = (float*)d_out;

    char* ws = (char*)d_ws;
    unsigned short* xn   = (unsigned short*)(ws);              // 8 MB  [4096,1024] bf16
    unsigned short* kvin = (unsigned short*)(ws + 8388608);    // 16 MB [4,2048,1024] bf16
    unsigned short* wqb  = (unsigned short*)(ws + 25165824);   // 2 MB
    unsigned short* wkvb = (unsigned short*)(ws + 27262976);   // 256 KB
    unsigned short* wob  = (unsigned short*)(ws + 27525120);   // 2 MB
    float* qg            = (float*)(ws + 29622272);            // 16 MB [4096,1024] f32
    float* kvg           = (float*)(ws + 46399488);            // 4 MB  [8192,128] f32
    unsigned short* kb   = (unsigned short*)(ws + 58982400);   // 1 MB  [B,J,DH] bf16
    unsigned short* vt   = (unsigned short*)(ws + 60030976);   // 1 MB  [B,DH,J] bf16
    unsigned short* ao   = (unsigned short*)(ws + 61079552);   // 8 MB  [4096,1024] bf16

    k_cvt3<<<2176, 256, 0, stream>>>(Wq, Wkv, Wo, wqb, wkvb, wob);
    k_ln_cvt<<<8192, 256, 0, stream>>>(x, prefix, gamma, xn, kvin);
    k_gemm_bt<<<dim3(16, 32), 256, 0, stream>>>(xn, wqb, qg, 1024, 1024);
    k_gemm_bt<<<dim3(2, 64), 256, 0, stream>>>(kvin, wkvb, kvg, 1024, 128);
    k_kv_epi<<<128, 256, 0, stream>>>(kvg, k_scale, kb, vt);
    k_attn<<<4096, 64, 0, stream>>>(qg, q_scale, kb, vt, bias, ao);
    k_gemm_bt<<<dim3(16, 32), 256, 0, stream>>>(ao, wob, out, 1024, 1024);
}